// Round 6
// baseline (827.012 us; speedup 1.0000x reference)
//
#include <hip/hip_runtime.h>
#include <stdint.h>

#define N_ROWS 131072
#define DIM 64
#define K_CODES 1024

typedef __attribute__((ext_vector_type(8))) short short8;
typedef __attribute__((ext_vector_type(4))) float float4v;

// ---------------- bf16 split helpers ----------------
__device__ __forceinline__ uint16_t f2bf(float f) {          // RTNE
    uint32_t u = __float_as_uint(f);
    u += 0x7fffu + ((u >> 16) & 1u);
    return (uint16_t)(u >> 16);
}
__device__ __forceinline__ float bf2f(uint16_t h) {
    return __uint_as_float(((uint32_t)h) << 16);
}

// ---------------- prep: split codebook hi/lo + transpose + sumc2 (one-time) ----------------
__global__ __launch_bounds__(256) void prep_kernel(
    const float* __restrict__ cb, float* __restrict__ sumc2,
    uint16_t* __restrict__ cbhi, uint16_t* __restrict__ cblo,
    uint16_t* __restrict__ cbT)
{
    __shared__ uint16_t tT[64][68];          // [dim][code], pad 68
    __shared__ float    ps[64][4];
    const int t    = threadIdx.x;
    const int code = t & 63;                 // code within 64-tile
    const int dq   = t >> 6;                 // dim quarter
    const int kb   = blockIdx.x * 64;
    const float4* src = reinterpret_cast<const float4*>(cb + (size_t)(kb + code) * DIM + dq * 16);
    float v[16];
    #pragma unroll
    for (int i = 0; i < 4; ++i) {
        float4 f4 = src[i];
        v[4*i+0]=f4.x; v[4*i+1]=f4.y; v[4*i+2]=f4.z; v[4*i+3]=f4.w;
    }
    float s = 0.f;
    short8 hv0, hv1, lv0, lv1;
    uint16_t hh[16];
    #pragma unroll
    for (int e = 0; e < 16; ++e) {
        s = fmaf(v[e], v[e], s);
        uint16_t h = f2bf(v[e]);
        uint16_t l = f2bf(v[e] - bf2f(h));
        hh[e] = h;
        if (e < 8) { hv0[e]   = (short)h; lv0[e]   = (short)l; }
        else       { hv1[e-8] = (short)h; lv1[e-8] = (short)l; }
    }
    const size_t rb = (size_t)(kb + code) * DIM + dq * 16;
    *(short8*)&cbhi[rb]     = hv0;  *(short8*)&cbhi[rb + 8] = hv1;
    *(short8*)&cblo[rb]     = lv0;  *(short8*)&cblo[rb + 8] = lv1;
    #pragma unroll
    for (int e = 0; e < 16; ++e) tT[dq*16 + e][code] = hh[e];
    ps[code][dq] = s;
    __syncthreads();
    if (t < 64) sumc2[kb + t] = (ps[t][0] + ps[t][1]) + (ps[t][2] + ps[t][3]);
    const int d = t >> 2, q = t & 3;
    *(short8*)&cbT[(size_t)d * K_CODES + kb + q*16]     = *(short8*)&tT[d][q*16];
    *(short8*)&cbT[(size_t)d * K_CODES + kb + q*16 + 8] = *(short8*)&tT[d][q*16 + 8];
}

// ---------------- threefry2x32 (JAX-compatible, key = (0,42)) ----------------
__device__ __forceinline__ uint32_t rotl32(uint32_t x, uint32_t r) {
    return (x << r) | (x >> (32u - r));
}
__device__ __forceinline__ void tf_round(uint32_t& x0, uint32_t& x1, uint32_t r) {
    x0 += x1; x1 = rotl32(x1, r); x1 ^= x0;
}
__device__ __forceinline__ void threefry2x32_k42(uint32_t c0, uint32_t c1,
                                                 uint32_t& o0, uint32_t& o1) {
    const uint32_t ks0 = 0u, ks1 = 42u, ks2 = 0x1BD11BDAu ^ 0u ^ 42u;
    uint32_t x0 = c0 + ks0, x1 = c1 + ks1;
    tf_round(x0,x1,13); tf_round(x0,x1,15); tf_round(x0,x1,26); tf_round(x0,x1,6);
    x0 += ks1; x1 += ks2 + 1u;
    tf_round(x0,x1,17); tf_round(x0,x1,29); tf_round(x0,x1,16); tf_round(x0,x1,24);
    x0 += ks2; x1 += ks0 + 2u;
    tf_round(x0,x1,13); tf_round(x0,x1,15); tf_round(x0,x1,26); tf_round(x0,x1,6);
    x0 += ks0; x1 += ks1 + 3u;
    tf_round(x0,x1,17); tf_round(x0,x1,29); tf_round(x0,x1,16); tf_round(x0,x1,24);
    x0 += ks1; x1 += ks2 + 4u;
    tf_round(x0,x1,13); tf_round(x0,x1,15); tf_round(x0,x1,26); tf_round(x0,x1,6);
    x0 += ks2; x1 += ks0 + 5u;
    o0 = x0; o1 = x1;
}

__device__ __forceinline__ float gumbel_from_bits(uint32_t bits) {
    uint32_t fb = (bits >> 9) | 0x3f800000u;
    float f = __uint_as_float(fb) - 1.0f;
    float u = fmaxf(1.17549435e-38f, f);
    float w = u - 1.0f;
    float p = fmaf(w, 0.2f, -0.25f);
    p = fmaf(w, p, 0.33333333333f);
    p = fmaf(w, p, -0.5f);
    p = fmaf(w, p, 1.0f);
    float v_poly = -(w * p);
    float v_log  = -__logf(u);
    float v = (u > 0.9375f) ? v_poly : v_log;
    return -__logf(v);
}

__device__ __forceinline__ void top2_ins(float d, int k, float& d1, int& k1, float& d2, int& k2) {
    if (d < d1)      { d2 = d1; k2 = k1; d1 = d; k1 = k; }
    else if (d < d2) { d2 = d; k2 = k; }
}

// ---------------- main: flash-style fused MFMA quantizer ----------------
// LDS: epoch A (init): xhi[4][16][72] @0, xlo @9216, xpart[4][16][4] @18432
//      loop:           pbuf[4][16][40] @0 (per-wave-private; no barrier needed,
//                      wave-lockstep + threadfence_block orders write->read)
// Codebook frags come straight from L2-resident pre-split global arrays.
// waves_per_eu(3,3): ~170-reg budget/wave so the unified VGPR/AGPR split has
// room for the ~110-reg peak -> no scratch spills (R3-R5 wrote ~350MB spill).
__global__ __launch_bounds__(256) __attribute__((amdgpu_waves_per_eu(3, 3)))
void quant_kernel(
    const float* __restrict__ x, const float* __restrict__ cb,
    const float* __restrict__ temp, const float* __restrict__ sumc2g,
    const uint16_t* __restrict__ cbhiG, const uint16_t* __restrict__ cbloG,
    const uint16_t* __restrict__ cbTG,
    float* __restrict__ out_emb, float* __restrict__ out_ids)
{
    __shared__ __align__(16) char smem[19456];
    uint16_t* const xhiP   = (uint16_t*)smem;            // [4][16][72]
    uint16_t* const xloP   = (uint16_t*)(smem + 9216);   // [4][16][72]
    float*    const xpartP = (float*)   (smem + 18432);  // [4][16][4]
    uint16_t* const pbufP  = (uint16_t*)smem;            // [4][16][40] (loop epoch)

    const int tid  = threadIdx.x;
    const int wave = tid >> 6;
    const int lane = tid & 63;
    const int quad = lane >> 4;
    const int col  = lane & 15;
    const float invT = 1.0f / temp[0];
    const int rowbase = blockIdx.x * 32 + wave * 8;

    // ---- epoch A: stage X tile + sumx2 partials (per-wave-private writes) ----
    {
        const int s = tid >> 2, w = s >> 4, t = s & 15, dq = tid & 3;
        const int row = blockIdx.x * 32 + w * 8 + (t >> 1) + ((t & 1) << 16);
        const float4* src = reinterpret_cast<const float4*>(x + (size_t)row * DIM + dq * 16);
        float v[16];
        #pragma unroll
        for (int i = 0; i < 4; ++i) {
            float4 f4 = src[i];
            v[4*i+0]=f4.x; v[4*i+1]=f4.y; v[4*i+2]=f4.z; v[4*i+3]=f4.w;
        }
        float psum = 0.f;
        short8 hv0, hv1, lv0, lv1;
        #pragma unroll
        for (int e = 0; e < 16; ++e) {
            psum = fmaf(v[e], v[e], psum);
            uint16_t h = f2bf(v[e]);
            uint16_t l = f2bf(v[e] - bf2f(h));
            if (e < 8) { hv0[e]   = (short)h; lv0[e]   = (short)l; }
            else       { hv1[e-8] = (short)h; lv1[e-8] = (short)l; }
        }
        const int rb = (w*16 + t)*72;
        *(short8*)&xhiP[rb + dq*16]     = hv0;
        *(short8*)&xhiP[rb + dq*16 + 8] = hv1;
        *(short8*)&xloP[rb + dq*16]     = lv0;
        *(short8*)&xloP[rb + dq*16 + 8] = lv1;
        xpartP[(w*16 + t)*4 + dq] = psum;
    }
    __syncthreads();

    const int arb = (wave*16 + col)*72;
    const short8 ahi0 = *(const short8*)&xhiP[arb + quad*8];
    const short8 ahi1 = *(const short8*)&xhiP[arb + 32 + quad*8];
    const short8 alo0 = *(const short8*)&xloP[arb + quad*8];
    const short8 alo1 = *(const short8*)&xloP[arb + 32 + quad*8];

    float sxr[4];
    #pragma unroll
    for (int j = 0; j < 4; ++j) {
        const float* xp = &xpartP[(wave*16 + quad*4 + j)*4];
        sxr[j] = (xp[0] + xp[1]) + (xp[2] + xp[3]);
    }
    __syncthreads();                 // all waves done with epoch A before pbuf reuse

    float m[4]  = {-3.0e38f, -3.0e38f, -3.0e38f, -3.0e38f};
    float Zp[4] = {0.f, 0.f, 0.f, 0.f};
    float4v e0 = {0,0,0,0}, e1 = {0,0,0,0}, e2 = {0,0,0,0}, e3 = {0,0,0,0};
    float d1[4] = {3.4e38f,3.4e38f,3.4e38f,3.4e38f};
    float d2[4] = {3.4e38f,3.4e38f,3.4e38f,3.4e38f};
    int   k1[4] = {0,0,0,0}, k2[4] = {0,0,0,0};

    const uint32_t n0 = (uint32_t)(rowbase + 2*quad);
    const uint32_t n1 = n0 + 1u;

    for (int blk = 0; blk < 32; ++blk) {
        const int kb = blk * 32;
        const int kc0 = kb + col, kc1 = kb + 16 + col;

        // ===== chunk 0: codes kb..kb+15 =====
        const size_t r0 = (size_t)kc0 << 6;
        const short8 bh00 = *(const short8*)&cbhiG[r0 + quad*8];
        const short8 bh01 = *(const short8*)&cbhiG[r0 + 32 + quad*8];
        const short8 bl00 = *(const short8*)&cbloG[r0 + quad*8];
        const short8 bl01 = *(const short8*)&cbloG[r0 + 32 + quad*8];
        const float  sc0  = sumc2g[kc0];

        float g0[4];                              // threefry hides chunk-0 load latency
        {
            uint32_t o0, o1, c;
            c = n0 * 1024u + (uint32_t)kc0;
            threefry2x32_k42(c, c + (1u << 26), o0, o1);
            g0[0] = gumbel_from_bits(o0); g0[1] = gumbel_from_bits(o1);
            c = n1 * 1024u + (uint32_t)kc0;
            threefry2x32_k42(c, c + (1u << 26), o0, o1);
            g0[2] = gumbel_from_bits(o0); g0[3] = gumbel_from_bits(o1);
        }

        float4v S0 = {0,0,0,0};
        S0 = __builtin_amdgcn_mfma_f32_16x16x32_bf16(ahi0, bh00, S0, 0,0,0);
        S0 = __builtin_amdgcn_mfma_f32_16x16x32_bf16(ahi1, bh01, S0, 0,0,0);
        S0 = __builtin_amdgcn_mfma_f32_16x16x32_bf16(ahi0, bl00, S0, 0,0,0);
        S0 = __builtin_amdgcn_mfma_f32_16x16x32_bf16(ahi1, bl01, S0, 0,0,0);
        S0 = __builtin_amdgcn_mfma_f32_16x16x32_bf16(alo0, bh00, S0, 0,0,0);
        S0 = __builtin_amdgcn_mfma_f32_16x16x32_bf16(alo1, bh01, S0, 0,0,0);

        // ===== chunk 1: codes kb+16..kb+31 =====
        const size_t r1 = (size_t)kc1 << 6;
        const short8 bh10 = *(const short8*)&cbhiG[r1 + quad*8];
        const short8 bh11 = *(const short8*)&cbhiG[r1 + 32 + quad*8];
        const short8 bl10 = *(const short8*)&cbloG[r1 + quad*8];
        const short8 bl11 = *(const short8*)&cbloG[r1 + 32 + quad*8];
        const float  sc1  = sumc2g[kc1];

        float g1[4];                              // threefry hides chunk-1 load latency
        {
            uint32_t o0, o1, c;
            c = n0 * 1024u + (uint32_t)kc1;
            threefry2x32_k42(c, c + (1u << 26), o0, o1);
            g1[0] = gumbel_from_bits(o0); g1[1] = gumbel_from_bits(o1);
            c = n1 * 1024u + (uint32_t)kc1;
            threefry2x32_k42(c, c + (1u << 26), o0, o1);
            g1[2] = gumbel_from_bits(o0); g1[3] = gumbel_from_bits(o1);
        }

        float l0[4];
        #pragma unroll
        for (int j = 0; j < 4; ++j) {             // consume S0 while chunk-1 MFMAs run
            float dist0 = (sxr[j] + sc0) - 2.0f * S0[j];
            top2_ins(dist0, kc0, d1[j], k1[j], d2[j], k2[j]);
            l0[j] = (g0[j] - dist0) * invT;
        }

        float4v S1 = {0,0,0,0};
        S1 = __builtin_amdgcn_mfma_f32_16x16x32_bf16(ahi0, bh10, S1, 0,0,0);
        S1 = __builtin_amdgcn_mfma_f32_16x16x32_bf16(ahi1, bh11, S1, 0,0,0);
        S1 = __builtin_amdgcn_mfma_f32_16x16x32_bf16(ahi0, bl10, S1, 0,0,0);
        S1 = __builtin_amdgcn_mfma_f32_16x16x32_bf16(ahi1, bl11, S1, 0,0,0);
        S1 = __builtin_amdgcn_mfma_f32_16x16x32_bf16(alo0, bh10, S1, 0,0,0);
        S1 = __builtin_amdgcn_mfma_f32_16x16x32_bf16(alo1, bh11, S1, 0,0,0);

        // GEMM2 B-frags issued here; softmax shuffles/exp below hide L2 latency
        const short8 bt0 = *(const short8*)&cbTG[(size_t)( col      ) * K_CODES + kb + quad*8];
        const short8 bt1 = *(const short8*)&cbTG[(size_t)( 16 + col ) * K_CODES + kb + quad*8];
        const short8 bt2 = *(const short8*)&cbTG[(size_t)( 32 + col ) * K_CODES + kb + quad*8];
        const short8 bt3 = *(const short8*)&cbTG[(size_t)( 48 + col ) * K_CODES + kb + quad*8];

        float l1[4], mn[4];
        #pragma unroll
        for (int j = 0; j < 4; ++j) {
            float dist1 = (sxr[j] + sc1) - 2.0f * S1[j];
            top2_ins(dist1, kc1, d1[j], k1[j], d2[j], k2[j]);
            l1[j] = (g1[j] - dist1) * invT;
            mn[j] = fmaxf(m[j], fmaxf(l0[j], l1[j]));
        }
        #pragma unroll
        for (int mask = 1; mask < 16; mask <<= 1) {
            #pragma unroll
            for (int j = 0; j < 4; ++j) mn[j] = fmaxf(mn[j], __shfl_xor(mn[j], mask));
        }
        float4v av;
        #pragma unroll
        for (int j = 0; j < 4; ++j) {
            float alpha = __expf(m[j] - mn[j]);
            m[j] = mn[j];
            av[j] = alpha;
            float p0 = __expf(l0[j] - mn[j]);
            float p1 = __expf(l1[j] - mn[j]);
            Zp[j] = fmaf(Zp[j], alpha, p0 + p1);
            pbufP[(wave*16 + quad*4 + j)*40 + col]      = f2bf(p0);
            pbufP[(wave*16 + quad*4 + j)*40 + 16 + col] = f2bf(p1);
        }
        e0 *= av; e1 *= av; e2 *= av; e3 *= av;
        __threadfence_block();                    // lgkmcnt drain: pbuf write->read
                                                  // (per-wave-private, lockstep wave)

        const short8 pa = *(const short8*)&pbufP[(wave*16 + col)*40 + quad*8];
        e0 = __builtin_amdgcn_mfma_f32_16x16x32_bf16(pa, bt0, e0, 0,0,0);
        e1 = __builtin_amdgcn_mfma_f32_16x16x32_bf16(pa, bt1, e1, 0,0,0);
        e2 = __builtin_amdgcn_mfma_f32_16x16x32_bf16(pa, bt2, e2, 0,0,0);
        e3 = __builtin_amdgcn_mfma_f32_16x16x32_bf16(pa, bt3, e3, 0,0,0);
    }

    // ---- epilogue, part 1: Z reduce + emb stores (kills accumulator liveness) ----
    #pragma unroll
    for (int mask = 1; mask < 16; mask <<= 1) {
        #pragma unroll
        for (int j = 0; j < 4; ++j) Zp[j] += __shfl_xor(Zp[j], mask);
    }
    #pragma unroll
    for (int j = 0; j < 4; ++j) {
        const int t = quad*4 + j;
        const int row = rowbase + (t >> 1) + ((t & 1) << 16);
        const float rZ = 1.0f / Zp[j];
        out_emb[(size_t)row * DIM +      col] = e0[j] * rZ;
        out_emb[(size_t)row * DIM + 16 + col] = e1[j] * rZ;
        out_emb[(size_t)row * DIM + 32 + col] = e2[j] * rZ;
        out_emb[(size_t)row * DIM + 48 + col] = e3[j] * rZ;
    }

    // ---- epilogue, part 2: top-2 merge + exact refine + ids ----
    #pragma unroll
    for (int mask = 1; mask < 16; mask <<= 1) {
        #pragma unroll
        for (int j = 0; j < 4; ++j) {
            float od1 = __shfl_xor(d1[j], mask);
            float od2 = __shfl_xor(d2[j], mask);
            int   ok1 = __shfl_xor(k1[j], mask);
            int   ok2 = __shfl_xor(k2[j], mask);
            bool mf = (d1[j] < od1) || (d1[j] == od1 && k1[j] < ok1);
            float b1  = mf ? d1[j] : od1;  int bk1 = mf ? k1[j] : ok1;
            float c1  = mf ? od1 : d1[j];  int ck1 = mf ? ok1 : k1[j];
            float c2  = mf ? d2[j] : od2;  int ck2 = mf ? k2[j] : ok2;
            bool s1 = (c1 < c2) || (c1 == c2 && ck1 < ck2);
            d1[j] = b1; k1[j] = bk1;
            d2[j] = s1 ? c1 : c2; k2[j] = s1 ? ck1 : ck2;
        }
    }
    #pragma unroll
    for (int j = 0; j < 4; ++j) {
        const int t = quad*4 + j;
        const int row = rowbase + (t >> 1) + ((t & 1) << 16);
        if (col == 0) {
            int kbest = k1[j];
            if (d2[j] - d1[j] < 1e-2f) {
                const float* xr = x + (size_t)row * DIM;
                double sx2 = 0.0;
                for (int d = 0; d < DIM; ++d) sx2 = fma((double)xr[d], (double)xr[d], sx2);
                double dd[2]; int kk[2] = {k1[j], k2[j]};
                for (int c = 0; c < 2; ++c) {
                    const float* crow = cb + (size_t)kk[c] * DIM;
                    double dot = 0.0, c2s = 0.0;
                    for (int d = 0; d < DIM; ++d) {
                        double cj = (double)crow[d];
                        c2s = fma(cj, cj, c2s);
                        dot = fma((double)xr[d], cj, dot);
                    }
                    dd[c] = sx2 + c2s - 2.0 * dot;
                }
                if (dd[1] < dd[0] || (dd[1] == dd[0] && k2[j] < k1[j])) kbest = k2[j];
            }
            out_ids[row] = (float)kbest;
        }
    }
}

extern "C" void kernel_launch(void* const* d_in, const int* in_sizes, int n_in,
                              void* d_out, int out_size, void* d_ws, size_t ws_size,
                              hipStream_t stream) {
    const float* x    = (const float*)d_in[0];
    const float* cb   = (const float*)d_in[1];
    const float* temp = (const float*)d_in[2];
    char* ws = (char*)d_ws;
    float*    sumc2 = (float*)ws;                        // 4 KB
    uint16_t* cbhi  = (uint16_t*)(ws + 4096);            // 128 KB
    uint16_t* cblo  = (uint16_t*)(ws + 135168);          // 128 KB
    uint16_t* cbT   = (uint16_t*)(ws + 266240);          // 128 KB
    float* out_emb  = (float*)d_out;
    float* out_ids  = (float*)d_out + (size_t)N_ROWS * DIM;

    prep_kernel<<<K_CODES / 64, 256, 0, stream>>>(cb, sumc2, cbhi, cblo, cbT);
    quant_kernel<<<N_ROWS / 64, 256, 0, stream>>>(x, cb, temp, sumc2, cbhi, cblo, cbT,
                                                  out_emb, out_ids);
}

// Round 7
// 678.042 us; speedup vs baseline: 1.2197x; 1.2197x over previous
//
#include <hip/hip_runtime.h>
#include <stdint.h>

#define N_ROWS 131072
#define DIM 64
#define K_CODES 1024

typedef __attribute__((ext_vector_type(8))) short short8;
typedef __attribute__((ext_vector_type(4))) float float4v;

// ---------------- bf16 split helpers ----------------
__device__ __forceinline__ uint16_t f2bf(float f) {          // RTNE
    uint32_t u = __float_as_uint(f);
    u += 0x7fffu + ((u >> 16) & 1u);
    return (uint16_t)(u >> 16);
}
__device__ __forceinline__ float bf2f(uint16_t h) {
    return __uint_as_float(((uint32_t)h) << 16);
}

// ---------------- prep: split codebook hi/lo + transpose + sumc2 (one-time) ----------------
__global__ __launch_bounds__(256) void prep_kernel(
    const float* __restrict__ cb, float* __restrict__ sumc2,
    uint16_t* __restrict__ cbhi, uint16_t* __restrict__ cblo,
    uint16_t* __restrict__ cbT)
{
    __shared__ uint16_t tT[64][68];          // [dim][code], pad 68
    __shared__ float    ps[64][4];
    const int t    = threadIdx.x;
    const int code = t & 63;                 // code within 64-tile
    const int dq   = t >> 6;                 // dim quarter
    const int kb   = blockIdx.x * 64;
    const float4* src = reinterpret_cast<const float4*>(cb + (size_t)(kb + code) * DIM + dq * 16);
    float v[16];
    #pragma unroll
    for (int i = 0; i < 4; ++i) {
        float4 f4 = src[i];
        v[4*i+0]=f4.x; v[4*i+1]=f4.y; v[4*i+2]=f4.z; v[4*i+3]=f4.w;
    }
    float s = 0.f;
    short8 hv0, hv1, lv0, lv1;
    uint16_t hh[16];
    #pragma unroll
    for (int e = 0; e < 16; ++e) {
        s = fmaf(v[e], v[e], s);
        uint16_t h = f2bf(v[e]);
        uint16_t l = f2bf(v[e] - bf2f(h));
        hh[e] = h;
        if (e < 8) { hv0[e]   = (short)h; lv0[e]   = (short)l; }
        else       { hv1[e-8] = (short)h; lv1[e-8] = (short)l; }
    }
    const size_t rb = (size_t)(kb + code) * DIM + dq * 16;
    *(short8*)&cbhi[rb]     = hv0;  *(short8*)&cbhi[rb + 8] = hv1;
    *(short8*)&cblo[rb]     = lv0;  *(short8*)&cblo[rb + 8] = lv1;
    #pragma unroll
    for (int e = 0; e < 16; ++e) tT[dq*16 + e][code] = hh[e];
    ps[code][dq] = s;
    __syncthreads();
    if (t < 64) sumc2[kb + t] = (ps[t][0] + ps[t][1]) + (ps[t][2] + ps[t][3]);
    const int d = t >> 2, q = t & 3;
    *(short8*)&cbT[(size_t)d * K_CODES + kb + q*16]     = *(short8*)&tT[d][q*16];
    *(short8*)&cbT[(size_t)d * K_CODES + kb + q*16 + 8] = *(short8*)&tT[d][q*16 + 8];
}

// ---------------- threefry2x32 (JAX-compatible, key = (0,42)) ----------------
__device__ __forceinline__ uint32_t rotl32(uint32_t x, uint32_t r) {
    return (x << r) | (x >> (32u - r));
}
__device__ __forceinline__ void tf_round(uint32_t& x0, uint32_t& x1, uint32_t r) {
    x0 += x1; x1 = rotl32(x1, r); x1 ^= x0;
}
__device__ __forceinline__ void threefry2x32_k42(uint32_t c0, uint32_t c1,
                                                 uint32_t& o0, uint32_t& o1) {
    const uint32_t ks0 = 0u, ks1 = 42u, ks2 = 0x1BD11BDAu ^ 0u ^ 42u;
    uint32_t x0 = c0 + ks0, x1 = c1 + ks1;
    tf_round(x0,x1,13); tf_round(x0,x1,15); tf_round(x0,x1,26); tf_round(x0,x1,6);
    x0 += ks1; x1 += ks2 + 1u;
    tf_round(x0,x1,17); tf_round(x0,x1,29); tf_round(x0,x1,16); tf_round(x0,x1,24);
    x0 += ks2; x1 += ks0 + 2u;
    tf_round(x0,x1,13); tf_round(x0,x1,15); tf_round(x0,x1,26); tf_round(x0,x1,6);
    x0 += ks0; x1 += ks1 + 3u;
    tf_round(x0,x1,17); tf_round(x0,x1,29); tf_round(x0,x1,16); tf_round(x0,x1,24);
    x0 += ks1; x1 += ks2 + 4u;
    tf_round(x0,x1,13); tf_round(x0,x1,15); tf_round(x0,x1,26); tf_round(x0,x1,6);
    x0 += ks2; x1 += ks0 + 5u;
    o0 = x0; o1 = x1;
}

__device__ __forceinline__ float gumbel_from_bits(uint32_t bits) {
    uint32_t fb = (bits >> 9) | 0x3f800000u;
    float f = __uint_as_float(fb) - 1.0f;
    float u = fmaxf(1.17549435e-38f, f);
    float w = u - 1.0f;
    float p = fmaf(w, 0.2f, -0.25f);
    p = fmaf(w, p, 0.33333333333f);
    p = fmaf(w, p, -0.5f);
    p = fmaf(w, p, 1.0f);
    float v_poly = -(w * p);
    float v_log  = -__logf(u);
    float v = (u > 0.9375f) ? v_poly : v_log;
    return -__logf(v);
}

__device__ __forceinline__ void top2_ins(float d, int k, float& d1, int& k1, float& d2, int& k2) {
    if (d < d1)      { d2 = d1; k2 = k1; d1 = d; k1 = k; }
    else if (d < d2) { d2 = d; k2 = k; }
}

// ---------------- main: fused MFMA quantizer, FIXED-OFFSET softmax ----------------
// Softmax is shift-invariant: weights = exp(l-M)/sum(exp(l-M)) for ANY M.
// Use a-priori M_row = (25 - sumx2)*invT -> exp arg = (g + 2*dot - sumc2 - 25)*invT
// which is bounded in [-82, +42] (|2 dot| <= 2*|x||c| <= 50, |c|^2 <= 5,
// g in [-2.3, 16.6]) -> no overflow/underflow of the max term in f32/bf16.
// This removes the per-iter cross-lane max reduction (4-deep ds_bpermute chain),
// the alpha rescale, and all cross-iteration serial coupling.
__global__ __launch_bounds__(256) __attribute__((amdgpu_waves_per_eu(4, 4)))
void quant_kernel(
    const float* __restrict__ x, const float* __restrict__ cb,
    const float* __restrict__ temp, const float* __restrict__ sumc2g,
    const uint16_t* __restrict__ cbhiG, const uint16_t* __restrict__ cbloG,
    const uint16_t* __restrict__ cbTG,
    float* __restrict__ out_emb, float* __restrict__ out_ids)
{
    __shared__ __align__(16) char smem[19456];
    uint16_t* const xhiP   = (uint16_t*)smem;            // [4][16][72]
    uint16_t* const xloP   = (uint16_t*)(smem + 9216);   // [4][16][72]
    float*    const xpartP = (float*)   (smem + 18432);  // [4][16][4]
    uint16_t* const pbufP  = (uint16_t*)smem;            // [4][16][40] (loop epoch)

    const int tid  = threadIdx.x;
    const int wave = tid >> 6;
    const int lane = tid & 63;
    const int quad = lane >> 4;
    const int col  = lane & 15;
    const float invT = 1.0f / temp[0];
    const int rowbase = blockIdx.x * 32 + wave * 8;

    // ---- epoch A: stage X tile + sumx2 partials ----
    {
        const int s = tid >> 2, w = s >> 4, t = s & 15, dq = tid & 3;
        const int row = blockIdx.x * 32 + w * 8 + (t >> 1) + ((t & 1) << 16);
        const float4* src = reinterpret_cast<const float4*>(x + (size_t)row * DIM + dq * 16);
        float v[16];
        #pragma unroll
        for (int i = 0; i < 4; ++i) {
            float4 f4 = src[i];
            v[4*i+0]=f4.x; v[4*i+1]=f4.y; v[4*i+2]=f4.z; v[4*i+3]=f4.w;
        }
        float psum = 0.f;
        short8 hv0, hv1, lv0, lv1;
        #pragma unroll
        for (int e = 0; e < 16; ++e) {
            psum = fmaf(v[e], v[e], psum);
            uint16_t h = f2bf(v[e]);
            uint16_t l = f2bf(v[e] - bf2f(h));
            if (e < 8) { hv0[e]   = (short)h; lv0[e]   = (short)l; }
            else       { hv1[e-8] = (short)h; lv1[e-8] = (short)l; }
        }
        const int rb = (w*16 + t)*72;
        *(short8*)&xhiP[rb + dq*16]     = hv0;
        *(short8*)&xhiP[rb + dq*16 + 8] = hv1;
        *(short8*)&xloP[rb + dq*16]     = lv0;
        *(short8*)&xloP[rb + dq*16 + 8] = lv1;
        xpartP[(w*16 + t)*4 + dq] = psum;
    }
    __syncthreads();

    const int arb = (wave*16 + col)*72;
    const short8 ahi0 = *(const short8*)&xhiP[arb + quad*8];
    const short8 ahi1 = *(const short8*)&xhiP[arb + 32 + quad*8];
    const short8 alo0 = *(const short8*)&xloP[arb + quad*8];
    const short8 alo1 = *(const short8*)&xloP[arb + 32 + quad*8];

    float sxr[4];
    #pragma unroll
    for (int j = 0; j < 4; ++j) {
        const float* xp = &xpartP[(wave*16 + quad*4 + j)*4];
        sxr[j] = (xp[0] + xp[1]) + (xp[2] + xp[3]);
    }
    __syncthreads();                 // all waves done with epoch A before pbuf reuse

    float Zp[4] = {0.f, 0.f, 0.f, 0.f};
    float4v e0 = {0,0,0,0}, e1 = {0,0,0,0}, e2 = {0,0,0,0}, e3 = {0,0,0,0};
    float d1[4] = {3.4e38f,3.4e38f,3.4e38f,3.4e38f};
    float d2[4] = {3.4e38f,3.4e38f,3.4e38f,3.4e38f};
    int   k1[4] = {0,0,0,0}, k2[4] = {0,0,0,0};

    const uint32_t n0 = (uint32_t)(rowbase + 2*quad);
    const uint32_t n1 = n0 + 1u;

    for (int blk = 0; blk < 32; ++blk) {
        const int kb = blk * 32;
        const int kc0 = kb + col, kc1 = kb + 16 + col;

        // ===== chunk 0: codes kb..kb+15 =====
        const size_t r0 = (size_t)kc0 << 6;
        const short8 bh00 = *(const short8*)&cbhiG[r0 + quad*8];
        const short8 bh01 = *(const short8*)&cbhiG[r0 + 32 + quad*8];
        const short8 bl00 = *(const short8*)&cbloG[r0 + quad*8];
        const short8 bl01 = *(const short8*)&cbloG[r0 + 32 + quad*8];
        const float  sc0  = sumc2g[kc0];

        float g0[4];                              // threefry hides chunk-0 load latency
        {
            uint32_t o0, o1, c;
            c = n0 * 1024u + (uint32_t)kc0;
            threefry2x32_k42(c, c + (1u << 26), o0, o1);
            g0[0] = gumbel_from_bits(o0); g0[1] = gumbel_from_bits(o1);
            c = n1 * 1024u + (uint32_t)kc0;
            threefry2x32_k42(c, c + (1u << 26), o0, o1);
            g0[2] = gumbel_from_bits(o0); g0[3] = gumbel_from_bits(o1);
        }

        float4v S0 = {0,0,0,0};
        S0 = __builtin_amdgcn_mfma_f32_16x16x32_bf16(ahi0, bh00, S0, 0,0,0);
        S0 = __builtin_amdgcn_mfma_f32_16x16x32_bf16(ahi1, bh01, S0, 0,0,0);
        S0 = __builtin_amdgcn_mfma_f32_16x16x32_bf16(ahi0, bl00, S0, 0,0,0);
        S0 = __builtin_amdgcn_mfma_f32_16x16x32_bf16(ahi1, bl01, S0, 0,0,0);
        S0 = __builtin_amdgcn_mfma_f32_16x16x32_bf16(alo0, bh00, S0, 0,0,0);
        S0 = __builtin_amdgcn_mfma_f32_16x16x32_bf16(alo1, bh01, S0, 0,0,0);

        // ===== chunk 1: codes kb+16..kb+31 =====
        const size_t r1 = (size_t)kc1 << 6;
        const short8 bh10 = *(const short8*)&cbhiG[r1 + quad*8];
        const short8 bh11 = *(const short8*)&cbhiG[r1 + 32 + quad*8];
        const short8 bl10 = *(const short8*)&cbloG[r1 + quad*8];
        const short8 bl11 = *(const short8*)&cbloG[r1 + 32 + quad*8];
        const float  sc1  = sumc2g[kc1];

        float g1[4];                              // threefry hides chunk-1 load latency
        {
            uint32_t o0, o1, c;
            c = n0 * 1024u + (uint32_t)kc1;
            threefry2x32_k42(c, c + (1u << 26), o0, o1);
            g1[0] = gumbel_from_bits(o0); g1[1] = gumbel_from_bits(o1);
            c = n1 * 1024u + (uint32_t)kc1;
            threefry2x32_k42(c, c + (1u << 26), o0, o1);
            g1[2] = gumbel_from_bits(o0); g1[3] = gumbel_from_bits(o1);
        }

        float p0v[4];
        #pragma unroll
        for (int j = 0; j < 4; ++j) {             // consume S0 while chunk-1 MFMAs run
            float dist0 = (sxr[j] + sc0) - 2.0f * S0[j];
            top2_ins(dist0, kc0, d1[j], k1[j], d2[j], k2[j]);
            // fixed-offset exp arg: (g - dist - M) = g + 2S - sc - 25  (sumx2 cancels)
            p0v[j] = __expf((g0[j] + 2.0f * S0[j] - sc0 - 25.0f) * invT);
        }

        float4v S1 = {0,0,0,0};
        S1 = __builtin_amdgcn_mfma_f32_16x16x32_bf16(ahi0, bh10, S1, 0,0,0);
        S1 = __builtin_amdgcn_mfma_f32_16x16x32_bf16(ahi1, bh11, S1, 0,0,0);
        S1 = __builtin_amdgcn_mfma_f32_16x16x32_bf16(ahi0, bl10, S1, 0,0,0);
        S1 = __builtin_amdgcn_mfma_f32_16x16x32_bf16(ahi1, bl11, S1, 0,0,0);
        S1 = __builtin_amdgcn_mfma_f32_16x16x32_bf16(alo0, bh10, S1, 0,0,0);
        S1 = __builtin_amdgcn_mfma_f32_16x16x32_bf16(alo1, bh11, S1, 0,0,0);

        // GEMM2 B-frags issued here; exp/pbuf VALU below hides L2 latency
        const short8 bt0 = *(const short8*)&cbTG[(size_t)( col      ) * K_CODES + kb + quad*8];
        const short8 bt1 = *(const short8*)&cbTG[(size_t)( 16 + col ) * K_CODES + kb + quad*8];
        const short8 bt2 = *(const short8*)&cbTG[(size_t)( 32 + col ) * K_CODES + kb + quad*8];
        const short8 bt3 = *(const short8*)&cbTG[(size_t)( 48 + col ) * K_CODES + kb + quad*8];

        #pragma unroll
        for (int j = 0; j < 4; ++j) {
            float dist1 = (sxr[j] + sc1) - 2.0f * S1[j];
            top2_ins(dist1, kc1, d1[j], k1[j], d2[j], k2[j]);
            float p1 = __expf((g1[j] + 2.0f * S1[j] - sc1 - 25.0f) * invT);
            float p0 = p0v[j];
            Zp[j] += p0 + p1;
            pbufP[(wave*16 + quad*4 + j)*40 + col]      = f2bf(p0);
            pbufP[(wave*16 + quad*4 + j)*40 + 16 + col] = f2bf(p1);
        }
        __threadfence_block();                    // pbuf write -> read ordering
                                                  // (per-wave-private, lockstep wave)

        const short8 pa = *(const short8*)&pbufP[(wave*16 + col)*40 + quad*8];
        e0 = __builtin_amdgcn_mfma_f32_16x16x32_bf16(pa, bt0, e0, 0,0,0);
        e1 = __builtin_amdgcn_mfma_f32_16x16x32_bf16(pa, bt1, e1, 0,0,0);
        e2 = __builtin_amdgcn_mfma_f32_16x16x32_bf16(pa, bt2, e2, 0,0,0);
        e3 = __builtin_amdgcn_mfma_f32_16x16x32_bf16(pa, bt3, e3, 0,0,0);
    }

    // ---- epilogue, part 1: Z reduce + emb stores ----
    #pragma unroll
    for (int mask = 1; mask < 16; mask <<= 1) {
        #pragma unroll
        for (int j = 0; j < 4; ++j) Zp[j] += __shfl_xor(Zp[j], mask);
    }
    #pragma unroll
    for (int j = 0; j < 4; ++j) {
        const int t = quad*4 + j;
        const int row = rowbase + (t >> 1) + ((t & 1) << 16);
        const float rZ = 1.0f / Zp[j];
        out_emb[(size_t)row * DIM +      col] = e0[j] * rZ;
        out_emb[(size_t)row * DIM + 16 + col] = e1[j] * rZ;
        out_emb[(size_t)row * DIM + 32 + col] = e2[j] * rZ;
        out_emb[(size_t)row * DIM + 48 + col] = e3[j] * rZ;
    }

    // ---- epilogue, part 2: top-2 merge + exact refine + ids ----
    #pragma unroll
    for (int mask = 1; mask < 16; mask <<= 1) {
        #pragma unroll
        for (int j = 0; j < 4; ++j) {
            float od1 = __shfl_xor(d1[j], mask);
            float od2 = __shfl_xor(d2[j], mask);
            int   ok1 = __shfl_xor(k1[j], mask);
            int   ok2 = __shfl_xor(k2[j], mask);
            bool mf = (d1[j] < od1) || (d1[j] == od1 && k1[j] < ok1);
            float b1  = mf ? d1[j] : od1;  int bk1 = mf ? k1[j] : ok1;
            float c1  = mf ? od1 : d1[j];  int ck1 = mf ? ok1 : k1[j];
            float c2  = mf ? d2[j] : od2;  int ck2 = mf ? k2[j] : ok2;
            bool s1 = (c1 < c2) || (c1 == c2 && ck1 < ck2);
            d1[j] = b1; k1[j] = bk1;
            d2[j] = s1 ? c1 : c2; k2[j] = s1 ? ck1 : ck2;
        }
    }
    #pragma unroll
    for (int j = 0; j < 4; ++j) {
        const int t = quad*4 + j;
        const int row = rowbase + (t >> 1) + ((t & 1) << 16);
        if (col == 0) {
            int kbest = k1[j];
            if (d2[j] - d1[j] < 1e-2f) {
                const float* xr = x + (size_t)row * DIM;
                double sx2 = 0.0;
                for (int d = 0; d < DIM; ++d) sx2 = fma((double)xr[d], (double)xr[d], sx2);
                double dd[2]; int kk[2] = {k1[j], k2[j]};
                for (int c = 0; c < 2; ++c) {
                    const float* crow = cb + (size_t)kk[c] * DIM;
                    double dot = 0.0, c2s = 0.0;
                    for (int d = 0; d < DIM; ++d) {
                        double cj = (double)crow[d];
                        c2s = fma(cj, cj, c2s);
                        dot = fma((double)xr[d], cj, dot);
                    }
                    dd[c] = sx2 + c2s - 2.0 * dot;
                }
                if (dd[1] < dd[0] || (dd[1] == dd[0] && k2[j] < k1[j])) kbest = k2[j];
            }
            out_ids[row] = (float)kbest;
        }
    }
}

extern "C" void kernel_launch(void* const* d_in, const int* in_sizes, int n_in,
                              void* d_out, int out_size, void* d_ws, size_t ws_size,
                              hipStream_t stream) {
    const float* x    = (const float*)d_in[0];
    const float* cb   = (const float*)d_in[1];
    const float* temp = (const float*)d_in[2];
    char* ws = (char*)d_ws;
    float*    sumc2 = (float*)ws;                        // 4 KB
    uint16_t* cbhi  = (uint16_t*)(ws + 4096);            // 128 KB
    uint16_t* cblo  = (uint16_t*)(ws + 135168);          // 128 KB
    uint16_t* cbT   = (uint16_t*)(ws + 266240);          // 128 KB
    float* out_emb  = (float*)d_out;
    float* out_ids  = (float*)d_out + (size_t)N_ROWS * DIM;

    prep_kernel<<<K_CODES / 64, 256, 0, stream>>>(cb, sumc2, cbhi, cblo, cbT);
    quant_kernel<<<N_ROWS / 64, 256, 0, stream>>>(x, cb, temp, sumc2, cbhi, cblo, cbT,
                                                  out_emb, out_ids);
}